// Round 2
// baseline (48.425 us; speedup 1.0000x reference)
//
#include <hip/hip_runtime.h>
#include <hip/hip_bf16.h>

#define BATCH 64
#define HH 32
#define WW 32
#define CIN 64
#define COUT 64
#define KFEAT 576   // 3*3*64, flattened as ci*9 + kh*3 + kw (ci major)

typedef __bf16 bf16x8 __attribute__((ext_vector_type(8)));
typedef float f32x4 __attribute__((ext_vector_type(4)));

static __device__ __forceinline__ ushort f2bf_bits(float f) {
  __bf16 b = (__bf16)f;
  return __builtin_bit_cast(ushort, b);
}

// One block per output pixel (h,w). 256 threads = 4 waves.
// Per-pixel GEMM: C[64b][64co] = patches[64b][576k] * K[576k][64co], K-permuted
// as k' = p*64 + ci (p = kh*3+kw). Patches staged in LDS (bf16, XOR-swizzled,
// TRIPLE-buffered: one barrier/pixel). Kernel weights (zero reuse) streamed
// global->reg bf16 frags, prefetched ONE PIXEL AHEAD so the HBM latency chain
// never feeds the MFMAs directly; loads are nontemporal so the 19 MB/XCD
// weight stream doesn't evict the ~3.1 MB L2-resident input slice.
__global__ __launch_bounds__(256, 4) void LocalConv_kernel(
    const float* __restrict__ in, const float* __restrict__ ker,
    const float* __restrict__ bias, float* __restrict__ out) {
  // A buffers: [3][64 rows][64 ci] bf16, row stride 128B, XOR-swizzled by
  // byte ^= ((row&7)<<4) to kill the stride-128B bank conflict (G4).
  __shared__ __align__(16) ushort Ab[3][64 * 64];

  const int orig = blockIdx.x;
  // XCD-aware swizzle (T1): 1024 blocks, 8 XCDs, 128 contiguous per XCD
  // -> each XCD covers 4 consecutive h rows (input slice ~3.1MB, L2-fits).
  const int hw = (orig & 7) * 128 + (orig >> 3);
  const int h = hw >> 5, w = hw & 31;
  const int tid = threadIdx.x;
  const int lane = tid & 63;
  const int wave = tid >> 6;

  const float* kerhw = ker + (size_t)hw * (KFEAT * COUT);
  const int co = wave * 16 + (lane & 15);  // this wave's co slice
  const int kgrp = lane >> 4;              // 0..3, k-group within frag

  float4 st[4];  // in-flight input staging regs (issue-early / write-late)

  auto issue = [&](int p) {
    const int hp = h + p / 3 - 1, wp = w + p % 3 - 1;
    const bool ok = ((unsigned)hp < (unsigned)HH) && ((unsigned)wp < (unsigned)WW);
    const float* src = in + ((size_t)hp * WW + wp) * CIN;
#pragma unroll
    for (int i = 0; i < 4; ++i) {
      const int c = i * 256 + tid;       // 0..1023 chunks of float4
      const int brow = c >> 4;           // batch row 0..63
      const int c16 = c & 15;            // float4 index within row
      if (ok) {
        st[i] = *reinterpret_cast<const float4*>(
            src + (size_t)brow * (HH * WW * CIN) + c16 * 4);
      } else {
        st[i] = make_float4(0.f, 0.f, 0.f, 0.f);  // SAME zero padding
      }
    }
  };

  auto writebuf = [&](int p) {
    ushort* buf = &Ab[p % 3][0];
#pragma unroll
    for (int i = 0; i < 4; ++i) {
      const int c = i * 256 + tid;
      const int brow = c >> 4, c16 = c & 15;
      union { ushort us[4]; uint2 u2; } pk;
      pk.us[0] = f2bf_bits(st[i].x);
      pk.us[1] = f2bf_bits(st[i].y);
      pk.us[2] = f2bf_bits(st[i].z);
      pk.us[3] = f2bf_bits(st[i].w);
      const int byteofs = brow * 128 + ((c16 * 8) ^ ((brow & 7) << 4));
      *reinterpret_cast<uint2*>(reinterpret_cast<char*>(buf) + byteofs) = pk.u2;
    }
  };

  // Weight fragments, double-buffered one pixel ahead (8 VGPRs total).
  bf16x8 wA[2], wB[2];
  auto loadw = [&](int p, bf16x8* wr) {
    // kernel element (ci,co) for pixel p lives at kerhw[ci*576 + p*64 + co]
    const float* kp = kerhw + p * COUT + co;
#pragma unroll
    for (int ks = 0; ks < 2; ++ks)
#pragma unroll
      for (int j = 0; j < 8; ++j)
        wr[ks][j] = (__bf16)__builtin_nontemporal_load(
            kp + (size_t)(ks * 32 + kgrp * 8 + j) * KFEAT);
  };

  f32x4 acc[4];
#pragma unroll
  for (int m = 0; m < 4; ++m) acc[m] = (f32x4){0.f, 0.f, 0.f, 0.f};

  // Prologue: stage pixel 0 into LDS, weights for pixel 0 into regs,
  // and get pixel 1's input loads in flight.
  issue(0);
  writebuf(0);
  loadw(0, wA);
  issue(1);
  __syncthreads();  // Ab[0] visible

#pragma unroll
  for (int p = 0; p < 9; ++p) {
    bf16x8* wc = (p & 1) ? wB : wA;  // static after full unroll (rule #20)
    bf16x8* wn = (p & 1) ? wA : wB;

    if (p < 8) writebuf(p + 1);   // st holds issue(p+1) data (1 pixel old)
    if (p < 7) issue(p + 2);      // input loads now 2 pixels ahead
    if (p < 8) loadw(p + 1, wn);  // weight loads 1 pixel ahead

    const ushort* buf = &Ab[p % 3][0];
#pragma unroll
    for (int ks = 0; ks < 2; ++ks) {  // two K=32 steps per pixel
      const bf16x8 bfrag = wc[ks];
#pragma unroll
      for (int m = 0; m < 4; ++m) {
        const int row = m * 16 + (lane & 15);
        const int byteofs =
            row * 128 + ((ks * 64 + kgrp * 16) ^ ((row & 7) << 4));
        bf16x8 afrag = *reinterpret_cast<const bf16x8*>(
            reinterpret_cast<const char*>(buf) + byteofs);
        acc[m] = __builtin_amdgcn_mfma_f32_16x16x32_bf16(afrag, bfrag, acc[m],
                                                         0, 0, 0);
      }
    }

    // One barrier per pixel: with 3 buffers, writebuf(p+1) touches a buffer
    // last read at compute(p-2), already separated by two barriers.
    __syncthreads();
  }

  // Epilogue: C/D layout (16x16x32): col = lane&15, row = (lane>>4)*4 + reg.
  const float bv = bias[hw * COUT + co];
#pragma unroll
  for (int m = 0; m < 4; ++m) {
#pragma unroll
    for (int r = 0; r < 4; ++r) {
      const int b = m * 16 + kgrp * 4 + r;
      out[((size_t)b * (HH * WW) + hw) * COUT + co] = acc[m][r] + bv;
    }
  }
}

extern "C" void kernel_launch(void* const* d_in, const int* in_sizes, int n_in,
                              void* d_out, int out_size, void* d_ws,
                              size_t ws_size, hipStream_t stream) {
  const float* in = (const float*)d_in[0];
  const float* ker = (const float*)d_in[1];
  const float* bias = (const float*)d_in[2];
  float* out = (float*)d_out;
  (void)in_sizes; (void)n_in; (void)out_size; (void)d_ws; (void)ws_size;
  LocalConv_kernel<<<dim3(HH * WW), dim3(256), 0, stream>>>(in, ker, bias, out);
}

// Round 3
// 39.308 us; speedup vs baseline: 1.2319x; 1.2319x over previous
//
#include <hip/hip_runtime.h>
#include <hip/hip_bf16.h>

#define BATCH 64
#define HH 32
#define WW 32
#define CIN 64
#define COUT 64
#define KFEAT 576   // 3*3*64, flattened as ci*9 + kh*3 + kw (ci major)

typedef __bf16 bf16x8 __attribute__((ext_vector_type(8)));
typedef float f32x4 __attribute__((ext_vector_type(4)));

static __device__ __forceinline__ ushort f2bf_bits(float f) {
  __bf16 b = (__bf16)f;
  return __builtin_bit_cast(ushort, b);
}

// One block per output pixel (h,w). 256 threads = 4 waves.
// Per-pixel GEMM: C[64b][64co] = patches[64b][576k] * K[576k][64co], K-permuted
// as k' = p*64 + ci (p = kh*3+kw). Patches staged in LDS (bf16, XOR-swizzled,
// double-buffered, 2 barriers/pixel — the proven round-1 structure).
// ROUND-3 DELTA (single change): weight loads are register-double-buffered ONE
// PIXEL AHEAD as raw f32 (cvt deferred to use so the prefetch issues without a
// waitcnt), removing the exposed HBM latency chain in front of the MFMAs.
__global__ __launch_bounds__(256, 4) void LocalConv_kernel(
    const float* __restrict__ in, const float* __restrict__ ker,
    const float* __restrict__ bias, float* __restrict__ out) {
  // A buffers: [2][64 rows][64 ci] bf16, row stride 128B, XOR-swizzled by
  // byte ^= ((row&7)<<4) to kill the stride-128B bank conflict (G4).
  __shared__ __align__(16) ushort Ab[2][64 * 64];

  const int orig = blockIdx.x;
  // XCD-aware swizzle (T1): 1024 blocks, 8 XCDs, 128 contiguous per XCD
  // -> each XCD covers 4 consecutive h rows (input slice ~3.1MB, L2-fits).
  const int hw = (orig & 7) * 128 + (orig >> 3);
  const int h = hw >> 5, w = hw & 31;
  const int tid = threadIdx.x;
  const int lane = tid & 63;
  const int wave = tid >> 6;

  const float* kerhw = ker + (size_t)hw * (KFEAT * COUT);
  const int co = wave * 16 + (lane & 15);  // this wave's co slice
  const int kgrp = lane >> 4;              // 0..3, k-group within frag

  float4 st[4];  // in-flight input staging regs (issue-early / write-late)

  auto issue = [&](int p) {
    const int hp = h + p / 3 - 1, wp = w + p % 3 - 1;
    const bool ok = ((unsigned)hp < (unsigned)HH) && ((unsigned)wp < (unsigned)WW);
    const float* src = in + ((size_t)hp * WW + wp) * CIN;
#pragma unroll
    for (int i = 0; i < 4; ++i) {
      const int c = i * 256 + tid;       // 0..1023 chunks of float4
      const int brow = c >> 4;           // batch row 0..63
      const int c16 = c & 15;            // float4 index within row
      if (ok) {
        st[i] = *reinterpret_cast<const float4*>(
            src + (size_t)brow * (HH * WW * CIN) + c16 * 4);
      } else {
        st[i] = make_float4(0.f, 0.f, 0.f, 0.f);  // SAME zero padding
      }
    }
  };

  auto writebuf = [&](int p) {
    ushort* buf = &Ab[p & 1][0];
#pragma unroll
    for (int i = 0; i < 4; ++i) {
      const int c = i * 256 + tid;
      const int brow = c >> 4, c16 = c & 15;
      union { ushort us[4]; uint2 u2; } pk;
      pk.us[0] = f2bf_bits(st[i].x);
      pk.us[1] = f2bf_bits(st[i].y);
      pk.us[2] = f2bf_bits(st[i].z);
      pk.us[3] = f2bf_bits(st[i].w);
      const int byteofs = brow * 128 + ((c16 * 8) ^ ((brow & 7) << 4));
      *reinterpret_cast<uint2*>(reinterpret_cast<char*>(buf) + byteofs) = pk.u2;
    }
  };

  // Weight prefetch: raw f32, double-buffered one pixel ahead (32 VGPRs).
  // Kept as floats so the prefetch is pure global_load_dword with no
  // dependent cvt forcing an early s_waitcnt; conversion happens at use.
  float wF0[16], wF1[16];
  auto loadw = [&](int p, float* wf) {
    // kernel element (ci,co) for pixel p lives at kerhw[ci*576 + p*64 + co]
    const float* kp = kerhw + p * COUT + co;
#pragma unroll
    for (int t = 0; t < 16; ++t) {
      const int ci = (t >> 3) * 32 + kgrp * 8 + (t & 7);
      wf[t] = kp[(size_t)ci * KFEAT];
    }
  };

  f32x4 acc[4];
#pragma unroll
  for (int m = 0; m < 4; ++m) acc[m] = (f32x4){0.f, 0.f, 0.f, 0.f};

  // Prologue: pixel 0 into LDS, pixel-0 weights in flight.
  issue(0);
  writebuf(0);
  loadw(0, wF0);
  __syncthreads();  // Ab[0] visible

#pragma unroll
  for (int p = 0; p < 9; ++p) {
    float* wc = (p & 1) ? wF1 : wF0;  // static after full unroll (rule #20)
    float* wn = (p & 1) ? wF0 : wF1;

    if (p < 8) {
      issue(p + 1);      // input loads for next pixel in flight
      loadw(p + 1, wn);  // weight loads for next pixel in flight
    }

    const ushort* buf = &Ab[p & 1][0];
#pragma unroll
    for (int ks = 0; ks < 2; ++ks) {  // two K=32 steps per pixel
      bf16x8 bfrag;
#pragma unroll
      for (int j = 0; j < 8; ++j) bfrag[j] = (__bf16)wc[ks * 8 + j];
#pragma unroll
      for (int m = 0; m < 4; ++m) {
        const int row = m * 16 + (lane & 15);
        const int byteofs =
            row * 128 + ((ks * 64 + kgrp * 16) ^ ((row & 7) << 4));
        bf16x8 afrag = *reinterpret_cast<const bf16x8*>(
            reinterpret_cast<const char*>(buf) + byteofs);
        acc[m] = __builtin_amdgcn_mfma_f32_16x16x32_bf16(afrag, bfrag, acc[m],
                                                         0, 0, 0);
      }
    }

    __syncthreads();  // all reads of Ab[p&1] done
    if (p < 8) {
      writebuf(p + 1);  // write Ab[(p+1)&1]
      __syncthreads();  // visible before compute(p+1)
    }
  }

  // Epilogue: C/D layout (16x16x32): col = lane&15, row = (lane>>4)*4 + reg.
  const float bv = bias[hw * COUT + co];
#pragma unroll
  for (int m = 0; m < 4; ++m) {
#pragma unroll
    for (int r = 0; r < 4; ++r) {
      const int b = m * 16 + kgrp * 4 + r;
      out[((size_t)b * (HH * WW) + hw) * COUT + co] = acc[m][r] + bv;
    }
  }
}

extern "C" void kernel_launch(void* const* d_in, const int* in_sizes, int n_in,
                              void* d_out, int out_size, void* d_ws,
                              size_t ws_size, hipStream_t stream) {
  const float* in = (const float*)d_in[0];
  const float* ker = (const float*)d_in[1];
  const float* bias = (const float*)d_in[2];
  float* out = (float*)d_out;
  (void)in_sizes; (void)n_in; (void)out_size; (void)d_ws; (void)ws_size;
  LocalConv_kernel<<<dim3(HH * WW), dim3(256), 0, stream>>>(in, ker, bias, out);
}